// Round 1
// baseline (233.555 us; speedup 1.0000x reference)
//
#include <hip/hip_runtime.h>

// Problem constants (fixed by the reference)
constexpr int Bn = 4, Nn = 5000, Kd = 20, Hh = 128;
constexpr int Ee = Nn * Kd;  // 100000

typedef __attribute__((ext_vector_type(8))) short bf16x8;
typedef __attribute__((ext_vector_type(4))) float f32x4;

__device__ __forceinline__ short f2bf(float f) {
  unsigned int u = __builtin_bit_cast(unsigned int, f);
  u += 0x7fffu + ((u >> 16) & 1u);  // RNE (finite inputs only)
  return (short)(u >> 16);
}

__device__ __forceinline__ bf16x8 cvt8(const float* __restrict__ p) {
  float4 lo = *reinterpret_cast<const float4*>(p);
  float4 hi = *reinterpret_cast<const float4*>(p + 4);
  bf16x8 r;
  r[0] = f2bf(lo.x); r[1] = f2bf(lo.y); r[2] = f2bf(lo.z); r[3] = f2bf(lo.w);
  r[4] = f2bf(hi.x); r[5] = f2bf(hi.y); r[6] = f2bf(hi.z); r[7] = f2bf(hi.w);
  return r;
}

__device__ __forceinline__ bf16x8 zero8() {
  bf16x8 r;
  #pragma unroll
  for (int i = 0; i < 8; ++i) r[i] = 0;
  return r;
}

// ---------------------------------------------------------------------------
// Kernel 0: convert weights to bf16, build fused bias vectors.
// biasA[h] = U_b[h] + iU_b[h]   (normal edge)
// biasB[h] = U_b[h] + W_ph[h]   (placeholder edge, inverse idx == E)
// ---------------------------------------------------------------------------
__global__ void __launch_bounds__(256) prep_kernel(
    const float* __restrict__ U_w, const float* __restrict__ iU_w,
    const float* __restrict__ Vf_w, const float* __restrict__ Vt_w,
    const float* __restrict__ U_b, const float* __restrict__ iU_b,
    const float* __restrict__ W_ph,
    short* __restrict__ Ubf, short* __restrict__ iUbf,
    short* __restrict__ Vfbf, short* __restrict__ Vtbf,
    float* __restrict__ biasA, float* __restrict__ biasB) {
  int t = blockIdx.x * blockDim.x + threadIdx.x;
  if (t < Hh * Hh) {
    Ubf[t]  = f2bf(U_w[t]);
    iUbf[t] = f2bf(iU_w[t]);
    Vfbf[t] = f2bf(Vf_w[t]);
    Vtbf[t] = f2bf(Vt_w[t]);
  }
  if (t < Hh) {
    biasA[t] = U_b[t] + iU_b[t];
    biasB[t] = U_b[t] + W_ph[t];
  }
}

// ---------------------------------------------------------------------------
// Kernel 1: Vx_from = x @ Vf_w^T, Vx_to = x @ Vt_w^T (no bias here; added in
// epilogue). Treat [B*N, H] as one GEMM. One wave = 16 rows x 128 cols.
// ---------------------------------------------------------------------------
__global__ void __launch_bounds__(256) vxproj_kernel(
    const float* __restrict__ x,
    const short* __restrict__ Vfbf, const short* __restrict__ Vtbf,
    const float* __restrict__ Vf_b, const float* __restrict__ Vt_b,
    float* __restrict__ VxF, float* __restrict__ VxT) {
  int wave = (int)((blockIdx.x * blockDim.x + threadIdx.x) >> 6);
  constexpr int NW = (Bn * Nn) / 16;  // 1250
  if (wave >= NW) return;
  int lane = threadIdx.x & 63;
  int r = lane & 15, kg = lane >> 4;
  int row0 = wave * 16;
  const float* xrow = x + (size_t)(row0 + r) * Hh;

  f32x4 accF[8], accT[8];
  #pragma unroll
  for (int ht = 0; ht < 8; ++ht) {
    accF[ht] = (f32x4)(0.0f);
    accT[ht] = (f32x4)(0.0f);
  }

  #pragma unroll
  for (int kk = 0; kk < 4; ++kk) {
    int k0 = kk * 32 + kg * 8;
    bf16x8 a = cvt8(xrow + k0);
    #pragma unroll
    for (int ht = 0; ht < 8; ++ht) {
      bf16x8 bF = *reinterpret_cast<const bf16x8*>(Vfbf + (ht * 16 + r) * Hh + k0);
      bf16x8 bT = *reinterpret_cast<const bf16x8*>(Vtbf + (ht * 16 + r) * Hh + k0);
      accF[ht] = __builtin_amdgcn_mfma_f32_16x16x32_bf16(a, bF, accF[ht], 0, 0, 0);
      accT[ht] = __builtin_amdgcn_mfma_f32_16x16x32_bf16(a, bT, accT[ht], 0, 0, 0);
    }
  }

  #pragma unroll
  for (int ht = 0; ht < 8; ++ht) {
    int h = ht * 16 + r;
    float bf = Vf_b[h], bt = Vt_b[h];
    #pragma unroll
    for (int i = 0; i < 4; ++i) {
      size_t row = (size_t)(row0 + kg * 4 + i);
      VxF[row * Hh + h] = accF[ht][i] + bf;
      VxT[row * Hh + h] = accT[ht][i] + bt;
    }
  }
}

// ---------------------------------------------------------------------------
// Kernel 2: main per-edge kernel.
// out[b,j,h] = e[b,j]·U_w[h] + (ph ? 0 : e[b,idx2]·iU_w[h])
//            + (ph ? U_b+W_ph : U_b+iU_b)[h]
//            + VxT[b, edge_index[b,j], h] + VxF[b, j/K, h]
// One wave = 32 edges (2 row-tiles of 16) x 128 h.
// ---------------------------------------------------------------------------
__global__ void __launch_bounds__(256) edge_kernel(
    const float* __restrict__ e,
    const int* __restrict__ edge_index,
    const int* __restrict__ inv_edge_index,
    const short* __restrict__ Ubf, const short* __restrict__ iUbf,
    const float* __restrict__ biasA, const float* __restrict__ biasB,
    const float* __restrict__ VxF, const float* __restrict__ VxT,
    float* __restrict__ out) {
  int wave = (int)((blockIdx.x * blockDim.x + threadIdx.x) >> 6);  // 0..12499
  int lane = threadIdx.x & 63;
  int r = lane & 15, kg = lane >> 4;
  constexpr int WPB = Ee / 32;  // 3125 waves per batch
  int b = wave / WPB;
  int j0 = (wave % WPB) * 32;
  const size_t ebase = (size_t)b * Ee;
  const float* ebat = e + ebase * Hh;

  // A-source rows for this lane (lane loads rows r of each 16-row tile)
  const float* a1row[2];
  const float* a2row[2];
  bool ph[2];
  #pragma unroll
  for (int rt = 0; rt < 2; ++rt) {
    int j = j0 + rt * 16 + r;
    a1row[rt] = ebat + (size_t)j * Hh;
    int idx2 = inv_edge_index[ebase + j];
    ph[rt] = (idx2 == Ee);
    a2row[rt] = ebat + (size_t)(ph[rt] ? 0 : idx2) * Hh;
  }

  f32x4 acc[2][8];
  #pragma unroll
  for (int rt = 0; rt < 2; ++rt)
    #pragma unroll
    for (int ht = 0; ht < 8; ++ht) acc[rt][ht] = (f32x4)(0.0f);

  #pragma unroll
  for (int kk = 0; kk < 4; ++kk) {
    int k0 = kk * 32 + kg * 8;
    bf16x8 a1[2], a2[2];
    #pragma unroll
    for (int rt = 0; rt < 2; ++rt) {
      a1[rt] = cvt8(a1row[rt] + k0);
      bf16x8 t = cvt8(a2row[rt] + k0);
      a2[rt] = ph[rt] ? zero8() : t;
    }
    #pragma unroll
    for (int ht = 0; ht < 8; ++ht) {
      bf16x8 bU = *reinterpret_cast<const bf16x8*>(Ubf + (ht * 16 + r) * Hh + k0);
      bf16x8 bI = *reinterpret_cast<const bf16x8*>(iUbf + (ht * 16 + r) * Hh + k0);
      #pragma unroll
      for (int rt = 0; rt < 2; ++rt) {
        acc[rt][ht] = __builtin_amdgcn_mfma_f32_16x16x32_bf16(a1[rt], bU, acc[rt][ht], 0, 0, 0);
        acc[rt][ht] = __builtin_amdgcn_mfma_f32_16x16x32_bf16(a2[rt], bI, acc[rt][ht], 0, 0, 0);
      }
    }
  }

  // Epilogue. D layout: col h = ht*16 + (lane&15), row = (lane>>4)*4 + i.
  #pragma unroll
  for (int rt = 0; rt < 2; ++rt) {
    const float* vtrow[4];
    const float* vfrow[4];
    bool isph[4];
    int jg[4];
    #pragma unroll
    for (int i = 0; i < 4; ++i) {
      int j = j0 + rt * 16 + kg * 4 + i;
      jg[i] = j;
      int ei = edge_index[ebase + j];
      int idx2 = inv_edge_index[ebase + j];
      isph[i] = (idx2 == Ee);
      vtrow[i] = VxT + ((size_t)b * Nn + ei) * Hh;
      vfrow[i] = VxF + ((size_t)b * Nn + j / Kd) * Hh;
    }
    #pragma unroll
    for (int ht = 0; ht < 8; ++ht) {
      int h = ht * 16 + r;
      float bA = biasA[h], bB = biasB[h];
      #pragma unroll
      for (int i = 0; i < 4; ++i) {
        float v = acc[rt][ht][i] + (isph[i] ? bB : bA) + vtrow[i][h] + vfrow[i][h];
        out[(ebase + (size_t)jg[i]) * Hh + h] = v;
      }
    }
  }
}

extern "C" void kernel_launch(void* const* d_in, const int* in_sizes, int n_in,
                              void* d_out, int out_size, void* d_ws, size_t ws_size,
                              hipStream_t stream) {
  const float* x   = (const float*)d_in[0];
  const float* e   = (const float*)d_in[1];
  const int* edge_index = (const int*)d_in[2];
  const int* inv_edge_index = (const int*)d_in[3];
  const float* U_w  = (const float*)d_in[4];
  const float* U_b  = (const float*)d_in[5];
  const float* Vf_w = (const float*)d_in[6];
  const float* Vf_b = (const float*)d_in[7];
  const float* Vt_w = (const float*)d_in[8];
  const float* Vt_b = (const float*)d_in[9];
  const float* iU_w = (const float*)d_in[10];
  const float* iU_b = (const float*)d_in[11];
  const float* W_ph = (const float*)d_in[12];
  float* out = (float*)d_out;

  // Workspace layout
  float* VxF   = (float*)d_ws;                         // B*N*H floats
  float* VxT   = VxF + (size_t)Bn * Nn * Hh;           // B*N*H floats
  float* biasA = VxT + (size_t)Bn * Nn * Hh;           // 128
  float* biasB = biasA + Hh;                           // 128
  short* Ubf   = (short*)(biasB + Hh);                 // 16384 shorts
  short* iUbf  = Ubf + Hh * Hh;
  short* Vfbf  = iUbf + Hh * Hh;
  short* Vtbf  = Vfbf + Hh * Hh;

  prep_kernel<<<dim3(64), dim3(256), 0, stream>>>(
      U_w, iU_w, Vf_w, Vt_w, U_b, iU_b, W_ph, Ubf, iUbf, Vfbf, Vtbf, biasA, biasB);

  vxproj_kernel<<<dim3(313), dim3(256), 0, stream>>>(
      x, Vfbf, Vtbf, Vf_b, Vt_b, VxF, VxT);

  edge_kernel<<<dim3((Bn * (Ee / 32)) / 4), dim3(256), 0, stream>>>(
      e, edge_index, inv_edge_index, Ubf, iUbf, biasA, biasB, VxF, VxT, out);
}